// Round 5
// baseline (618.664 us; speedup 1.0000x reference)
//
#include <hip/hip_runtime.h>

#define DIM 64
#define NF 14
#define NOUT 105
#define NN 8192
#define NE 16384
#define NB 256
#define NS 2048
#define NJ 1024
#define KTOT 4160   // 4096 bilinear + 64 bias-fold rows

// ---- internal bf16 arena element offsets ----
#define C_X      0
#define C_EA     114688
#define C_L0W    180224
#define C_L0B    181120
#define C_NW1    181184
#define C_NB1    181440
#define C_NW2    181504
#define C_NB2    443648
#define C_CRT    447744
#define C_CB     451840
#define C_GWIH   451904
#define C_GWHH   464192
#define C_GBIH   476480
#define C_GBHH   476672
#define C_SW1    476864
#define C_SB1    480960
#define C_SW2    481024
#define C_SB2    487744
#define C_JW1    487856
#define C_JB1    491952
#define C_JW2    492016
#define C_JB2    492080
#define C_S2IH   492088
#define C_S2HH   492344
#define C_LOW    492600
#define C_LOB    492856
#define C_TOT    492864

typedef float f32x4 __attribute__((ext_vector_type(4)));
typedef short bf16x8 __attribute__((ext_vector_type(8)));

__device__ __forceinline__ float bf2f(unsigned short u){
  union { unsigned int i; float f; } v; v.i = ((unsigned int)u) << 16; return v.f;
}
__device__ __forceinline__ unsigned short f2bf(float f){
  union { float f; unsigned int i; } v; v.f = f;
  unsigned int x = v.i;
  return (unsigned short)((x + 0x7FFFu + ((x >> 16) & 1u)) >> 16);
}
__device__ __forceinline__ float sigm(float x){ return 1.f / (1.f + __expf(-x)); }
__device__ __forceinline__ float tanh_f(float x){
  x = fminf(10.f, fmaxf(-10.f, x));
  float e = __expf(2.f * x);
  return (e - 1.f) / (e + 1.f);
}
__device__ __forceinline__ float lrelu(float x){ return x > 0.f ? x : 0.01f * x; }

__device__ __forceinline__ float wred_sum(float v){
  #pragma unroll
  for (int off = 32; off > 0; off >>= 1) v += __shfl_xor(v, off, 64);
  return v;
}
__device__ __forceinline__ float wred_max(float v){
  #pragma unroll
  for (int off = 32; off > 0; off >>= 1) v = fmaxf(v, __shfl_xor(v, off, 64));
  return v;
}

// ---------------- dtype detect + convert ----------------

__global__ void k_detect(const unsigned short* __restrict__ ea, int* __restrict__ flag){
  __shared__ int cnt;
  if (threadIdx.x == 0) cnt = 0;
  __syncthreads();
  int c = 0;
  for (int i = threadIdx.x; i < 8192; i += 256) c += (ea[2*i] >> 15) & 1;
  atomicAdd(&cnt, c);
  __syncthreads();
  if (threadIdx.x == 0) *flag = (cnt > 100) ? 1 : 0;  // 1 => inputs are fp32
}

struct CvtArgs {
  const void* src[26];
  int n[26];
  int off[26];
};

__global__ void k_cvt(CvtArgs a, const int* __restrict__ flag, unsigned short* __restrict__ dst){
  bool f32 = (*flag != 0);
  int gid = blockIdx.x * blockDim.x + threadIdx.x, gs = gridDim.x * blockDim.x;
  #pragma unroll 1
  for (int j = 0; j < 26; ++j){
    const void* s = a.src[j];
    int n = a.n[j], o = a.off[j];
    for (int i = gid; i < n; i += gs)
      dst[o + i] = f32 ? f2bf(((const float*)s)[i]) : ((const unsigned short*)s)[i];
  }
}

// ---------------- fused setup: lin0 | edge-net-1 | w2rt build | deg | prep ----------------
// block ranges: [0,2048) lin0, [2048,6144) u/z, [6144,7184) w2rt, [7184,7248) deg, [7248] prep
#define SETUP_BLOCKS 7249

__global__ __launch_bounds__(256) void k_setup(const unsigned short* __restrict__ cvt,
                       const int* __restrict__ ei,
                       float* __restrict__ deg,
                       float* __restrict__ actF, unsigned short* __restrict__ actB,
                       unsigned short* __restrict__ z,
                       unsigned short* __restrict__ w2rt,
                       unsigned short* __restrict__ crt, unsigned short* __restrict__ btg,
                       float* __restrict__ cbg, float* __restrict__ qv){
  int bid = blockIdx.x, tid = threadIdx.x;
  if (bid < 2048){
    const unsigned short* x = cvt + C_X;
    const unsigned short* w = cvt + C_L0W;
    const unsigned short* b = cvt + C_L0B;
    int idx = bid * 256 + tid;
    int n = idx >> 6, d = idx & 63;
    float acc = bf2f(b[d]);
    #pragma unroll
    for (int f = 0; f < NF; ++f) acc += bf2f(x[n*NF + f]) * bf2f(w[f*DIM + d]);
    float v = lrelu(acc);
    actF[idx] = v; actB[idx] = f2bf(v);
  } else if (bid < 6144){
    const unsigned short* ea = cvt + C_EA;
    const unsigned short* w  = cvt + C_NW1;
    const unsigned short* b  = cvt + C_NB1;
    int idx = (bid - 2048) * 256 + tid;
    int e = idx >> 6, d = idx & 63;
    float acc = bf2f(b[d]);
    #pragma unroll
    for (int f = 0; f < 4; ++f) acc += bf2f(ea[e*4 + f]) * bf2f(w[f*DIM + d]);
    z[idx] = f2bf(lrelu(acc));
  } else if (bid < 7184){
    // W2 row-major by output o: w2rt[o][k], k = kz*64 + i  (4096 bilinear) then 64 bias rows
    int idx = (bid - 6144) * 256 + tid;   // exactly 64*KTOT
    const unsigned short* w2 = cvt + C_NW2;
    const unsigned short* b2 = cvt + C_NB2;
    int o = idx / KTOT, k = idx - o * KTOT;
    w2rt[idx] = (k < 4096) ? w2[(k >> 6) * 4096 + (k & 63) * 64 + o]
                           : b2[(k - 4096) * 64 + o];
  } else if (bid < 7248){
    int e = (bid - 7184) * 256 + tid;
    if (e < NE) atomicAdd(&deg[ei[NE + e]], 1.0f);
  } else {
    const unsigned short* cr  = cvt + C_CRT;
    const unsigned short* wih = cvt + C_GWIH;
    const unsigned short* whh = cvt + C_GWHH;
    const unsigned short* bih = cvt + C_GBIH;
    const unsigned short* bhh = cvt + C_GBHH;
    const unsigned short* s2sbih = cvt + C_S2IH;
    const unsigned short* s2sbhh = cvt + C_S2HH;
    for (int t = tid; t < 4096; t += 256){ int n = t & 63, k = t >> 6; crt[n*64 + k] = cr[k*64 + n]; }
    for (int t = tid; t < 32768; t += 256){
      int nidx = t >> 7, kidx = t & 127;
      int g = nidx >> 6, d = nidx & 63, ki = kidx & 63;
      unsigned short v = 0;
      if (kidx < 64){
        if (g == 0) v = wih[ki*192 + d];
        else if (g == 1) v = wih[ki*192 + 64 + d];
        else if (g == 2) v = wih[ki*192 + 128 + d];
      } else {
        if (g == 0) v = whh[ki*192 + d];
        else if (g == 1) v = whh[ki*192 + 64 + d];
        else if (g == 3) v = whh[ki*192 + 128 + d];
      }
      btg[nidx*128 + kidx] = v;
    }
    if (tid < 256){
      int g = tid >> 6, d = tid & 63;
      float v;
      if (g == 0) v = bf2f(bih[d]) + bf2f(bhh[d]);
      else if (g == 1) v = bf2f(bih[64 + d]) + bf2f(bhh[64 + d]);
      else if (g == 2) v = bf2f(bih[128 + d]);
      else v = bf2f(bhh[128 + d]);
      cbg[tid] = v;
    }
    if (tid < 64){
      float gi = bf2f(s2sbih[tid])       + bf2f(s2sbhh[tid]);
      float gg = bf2f(s2sbih[128 + tid]) + bf2f(s2sbhh[128 + tid]);
      float go = bf2f(s2sbih[192 + tid]) + bf2f(s2sbhh[192 + tid]);
      float c = sigm(gi) * tanh_f(gg);
      qv[tid] = sigm(go) * tanh_f(c);
    }
  }
}

// ---------------- per-iteration message: fused rank-1 bilinear GEMM, barrier/LDS-free ----------------
// msg[e][o] = sum_{kz,i} z[e][kz] * act[src][i] * W2[kz][i*64+o]  (+ bias rows with zf=1).
// Wave = 32 edges (2 m-tiles) x 8 kz-units (K=512). 512 edge-groups x 8 K-partitions = 4096 waves
// packed as 1024 blocks x 4 independent waves (no LDS, no barriers) -> 16 waves/CU resident.
// B read straight from L2-resident w2rt; u-loop fully unrolled so z is one 16B reg load per m-tile.

__global__ __launch_bounds__(256, 4) void k_msg(const unsigned short* __restrict__ actB,
                                                const unsigned short* __restrict__ z,
                                                const unsigned short* __restrict__ w2rt,
                                                const int* __restrict__ ei,
                                                float* __restrict__ agg){
  int w = threadIdx.x >> 6, lane = threadIdx.x & 63;
  int lm = lane & 15, q8 = (lane >> 4) * 8, rq = (lane >> 4) * 4;
  int waveId = blockIdx.x * 4 + w;
  int grp = waveId >> 3;      // [0,512): 32-edge groups
  int p   = waveId & 7;       // [0,8): K-partitions
  int e0  = grp * 32;
  int kz0 = p * 8;

  // A-operand act rows (16 rows per m-tile, 128B coalesced gather per row)
  uint4 ap[2][2];
  int rowe[2];
  #pragma unroll
  for (int mt = 0; mt < 2; ++mt){
    rowe[mt] = e0 + mt*16 + lm;
    int srcn = ei[rowe[mt]];
    ap[mt][0] = *(const uint4*)&actB[(size_t)srcn*64 + q8];
    ap[mt][1] = *(const uint4*)&actB[(size_t)srcn*64 + 32 + q8];
  }
  // z for this partition: the 8 kz scalars per row in one 16B load
  bf16x8 zv[2];
  #pragma unroll
  for (int mt = 0; mt < 2; ++mt)
    zv[mt] = *(const bf16x8*)&z[(size_t)rowe[mt]*64 + kz0];

  // per-lane w2rt row bases (col = nt*16+lm)
  const unsigned short* wrow[4];
  #pragma unroll
  for (int nt = 0; nt < 4; ++nt)
    wrow[nt] = w2rt + (size_t)(nt*16 + lm)*KTOT + q8;

  f32x4 acc[2][4];
  #pragma unroll
  for (int mt = 0; mt < 2; ++mt)
    #pragma unroll
    for (int nt = 0; nt < 4; ++nt) acc[mt][nt] = (f32x4){0.f, 0.f, 0.f, 0.f};

  #pragma unroll
  for (int u = 0; u < 8; ++u){          // compile-time u: zv lane index is static
    int kz = kz0 + u;
    #pragma unroll
    for (int h = 0; h < 2; ++h){
      bf16x8 bfr[4];
      #pragma unroll
      for (int nt = 0; nt < 4; ++nt)
        bfr[nt] = *(const bf16x8*)&wrow[nt][kz*64 + h*32];
      #pragma unroll
      for (int mt = 0; mt < 2; ++mt){
        float zf = bf2f((unsigned short)zv[mt][u]);
        const unsigned int* apw = (const unsigned int*)&ap[mt][h];
        bf16x8 af;
        #pragma unroll
        for (int hh = 0; hh < 4; ++hh){
          float flo = __uint_as_float(apw[hh] << 16) * zf;
          float fhi = __uint_as_float(apw[hh] & 0xFFFF0000u) * zf;
          unsigned int pk;
          asm("v_cvt_pk_bf16_f32 %0, %1, %2" : "=v"(pk) : "v"(flo), "v"(fhi));
          ((unsigned int*)&af)[hh] = pk;
        }
        #pragma unroll
        for (int nt = 0; nt < 4; ++nt)
          acc[mt][nt] = __builtin_amdgcn_mfma_f32_16x16x32_bf16(af, bfr[nt], acc[mt][nt], 0, 0, 0);
      }
    }
  }
  if (p == 7){
    // bias kz-unit (k 4096..4159): A = act directly (zf = 1)
    #pragma unroll
    for (int h = 0; h < 2; ++h){
      bf16x8 bfr[4];
      #pragma unroll
      for (int nt = 0; nt < 4; ++nt)
        bfr[nt] = *(const bf16x8*)&wrow[nt][4096 + h*32];
      #pragma unroll
      for (int mt = 0; mt < 2; ++mt){
        bf16x8 af = *(const bf16x8*)&ap[mt][h];
        #pragma unroll
        for (int nt = 0; nt < 4; ++nt)
          acc[mt][nt] = __builtin_amdgcn_mfma_f32_16x16x32_bf16(af, bfr[nt], acc[mt][nt], 0, 0, 0);
      }
    }
  }
  // scatter-accumulate partial sums (32 MB/launch total, fire-and-forget)
  #pragma unroll
  for (int mt = 0; mt < 2; ++mt){
    int dstv[4];
    #pragma unroll
    for (int r = 0; r < 4; ++r) dstv[r] = ei[NE + e0 + mt*16 + rq + r];
    #pragma unroll
    for (int nt = 0; nt < 4; ++nt)
      #pragma unroll
      for (int r = 0; r < 4; ++r)
        atomicAdd(&agg[(size_t)dstv[r]*64 + nt*16 + lm], acc[mt][nt][r]);
  }
}

// ---------------- per-iteration: fused conv_root + GRU (4 waves / 16 nodes) ----------------

__global__ __launch_bounds__(256) void k_gru(const unsigned short* __restrict__ actB_in,
                                             const float* __restrict__ actF_in,
                                             float* __restrict__ agg, const float* __restrict__ deg,
                                             const unsigned short* __restrict__ crt,
                                             const unsigned short* __restrict__ cvt,
                                             const unsigned short* __restrict__ btg,
                                             const float* __restrict__ cbg,
                                             float* __restrict__ actF_out, unsigned short* __restrict__ actB_out){
  const unsigned short* cbias = cvt + C_CB;
  __shared__ __align__(16) unsigned short s_frag[2*4*16*8];  // [kk][q][row][j] A-fragment order
  int w = threadIdx.x >> 6, lane = threadIdx.x & 63;
  int lm = lane & 15, q = lane >> 4;
  int q8 = q*8, rq = q*4;
  int r0 = blockIdx.x * 16;
  // phase 1: wave w computes m for cols [w*16, w*16+16)
  f32x4 am = (f32x4){0.f, 0.f, 0.f, 0.f};
  #pragma unroll
  for (int kk = 0; kk < 2; ++kk){
    bf16x8 a = *(const bf16x8*)&actB_in[(size_t)(r0 + lm)*64 + kk*32 + q8];
    bf16x8 b = *(const bf16x8*)&crt[(size_t)(w*16 + lm)*64 + kk*32 + q8];
    am = __builtin_amdgcn_mfma_f32_16x16x32_bf16(a, b, am, 0, 0, 0);
  }
  {
    int col = w*16 + lm;
    float cb = bf2f(cbias[col]);
    int kk2 = w >> 1, q2 = (w & 1)*2 + (lm >> 3), j = lm & 7;
    #pragma unroll
    for (int r = 0; r < 4; ++r){
      int row = r0 + rq + r;
      float dg = fmaxf(deg[row], 1.f);
      float v = am[r] + agg[(size_t)row*64 + col] / dg + cb;
      agg[(size_t)row*64 + col] = 0.f;   // clear for next iteration
      s_frag[((kk2*4 + q2)*16 + (rq + r))*8 + j] = f2bf(lrelu(v));
    }
  }
  __syncthreads();
  // phase 2: wave w computes gate n-tiles {0,1,2,3}*64 + w*16  (r,z,inn,hn for d-cols w*16..)
  f32x4 g[4];
  #pragma unroll
  for (int t = 0; t < 4; ++t) g[t] = (f32x4){0.f, 0.f, 0.f, 0.f};
  #pragma unroll
  for (int kk = 0; kk < 4; ++kk){
    bf16x8 a;
    if (kk < 2) a = *(const bf16x8*)&s_frag[(kk*4 + q)*128 + lm*8];
    else        a = *(const bf16x8*)&actB_in[(size_t)(r0 + lm)*64 + (kk - 2)*32 + q8];
    #pragma unroll
    for (int t = 0; t < 4; ++t){
      bf16x8 b = *(const bf16x8*)&btg[(size_t)(t*64 + w*16 + lm)*128 + kk*32 + q8];
      g[t] = __builtin_amdgcn_mfma_f32_16x16x32_bf16(a, b, g[t], 0, 0, 0);
    }
  }
  {
    int d = w*16 + lm;
    float cb_r = cbg[d], cb_z = cbg[64 + d], cb_n = cbg[128 + d], cb_h = cbg[192 + d];
    #pragma unroll
    for (int r = 0; r < 4; ++r){
      int row = r0 + rq + r;
      float rr = sigm(g[0][r] + cb_r);
      float zz = sigm(g[1][r] + cb_z);
      float nn = tanh_f(g[2][r] + cb_n + rr * (g[3][r] + cb_h));
      float ho = actF_in[(size_t)row*64 + d];
      float hn2 = (1.f - zz) * nn + zz * ho;
      actF_out[(size_t)row*64 + d] = hn2;
      actB_out[(size_t)row*64 + d] = f2bf(hn2);
    }
  }
}

// ---------------- fused final heads ----------------
// blocks [0,512): stem (4/block) | [512,768): jbond (4/block) | [768,832): graph (4/block, 1 wave each)

__device__ __forceinline__ int lower_bound_batch(const int* b, int val){
  int lo = 0, hi = NN;
  while (lo < hi){ int mid = (lo + hi) >> 1; if (b[mid] < val) lo = mid + 1; else hi = mid; }
  return lo;
}

__device__ __forceinline__ void store_out(void* outp, const int* flag, size_t idx, float v){
  if (*flag) ((float*)outp)[idx] = v;
  else       ((unsigned short*)outp)[idx] = f2bf(v);
}

__global__ __launch_bounds__(256) void k_heads(const float* __restrict__ act,
                                               const int* __restrict__ batch,
                                               const float* __restrict__ qv,
                                               const int* __restrict__ sidx,
                                               const int* __restrict__ jidx,
                                               const unsigned short* __restrict__ cvt,
                                               const int* __restrict__ flag,
                                               void* __restrict__ outp){
  int bid = blockIdx.x;
  int w = threadIdx.x >> 6, lane = threadIdx.x & 63;
  if (bid < 512){
    const unsigned short* w1 = cvt + C_SW1;
    const unsigned short* b1 = cvt + C_SB1;
    const unsigned short* w2 = cvt + C_SW2;
    const unsigned short* b2 = cvt + C_SB2;
    __shared__ float sa[4][64], st[4][64];
    int s = bid * 4 + w;
    int a = sidx[s];
    sa[w][lane] = act[(size_t)a*64 + lane];
    __syncthreads();
    float t = bf2f(b1[lane]);
    #pragma unroll 8
    for (int i = 0; i < 64; ++i) t += sa[w][i] * bf2f(w1[i*64 + lane]);
    st[w][lane] = lrelu(t);
    __syncthreads();
    size_t base = 512 + (size_t)s * NOUT;
    float v = bf2f(b2[lane]);
    #pragma unroll 8
    for (int d = 0; d < 64; ++d) v += st[w][d] * bf2f(w2[d*NOUT + lane]);
    store_out(outp, flag, base + lane, v);
    int o2 = 64 + lane;
    if (o2 < NOUT){
      float v2 = bf2f(b2[o2]);
      #pragma unroll 8
      for (int d = 0; d < 64; ++d) v2 += st[w][d] * bf2f(w2[d*NOUT + o2]);
      store_out(outp, flag, base + o2, v2);
    }
  } else if (bid < 768){
    const unsigned short* w1 = cvt + C_JW1;
    const unsigned short* b1 = cvt + C_JB1;
    const unsigned short* w2 = cvt + C_JW2;
    const unsigned short* b2 = cvt + C_JB2;
    __shared__ float a0[4][64], a1[4][64];
    int j = (bid - 512) * 4 + w;
    int i0 = jidx[j*2], i1 = jidx[j*2 + 1];
    a0[w][lane] = act[(size_t)i0*64 + lane];
    a1[w][lane] = act[(size_t)i1*64 + lane];
    __syncthreads();
    float t0 = bf2f(b1[lane]), t1 = t0;
    #pragma unroll 8
    for (int i = 0; i < 64; ++i){
      float wv = bf2f(w1[i*64 + lane]);
      t0 += a0[w][i] * wv;
      t1 += a1[w][i] * wv;
    }
    t0 = lrelu(t0); t1 = lrelu(t1);
    float p = (t0 + t1) * bf2f(w2[lane]);
    p = wred_sum(p);
    if (lane == 0) store_out(outp, flag, 512 + (size_t)NS*NOUT + j, 0.5f * p + bf2f(b2[0]));
  } else {
    const unsigned short* lw = cvt + C_LOW;
    const unsigned short* lb = cvt + C_LOB;
    __shared__ float se[4][512];
    int b = (bid - 768) * 4 + w;
    int lo = lower_bound_batch(batch, b);
    int hi = lower_bound_batch(batch, b + 1);
    int cnt = hi - lo; if (cnt > 512) cnt = 512;
    float qvl = qv[lane];
    for (int ii = 0; ii < cnt; ++ii){
      float p = act[(size_t)(lo + ii)*64 + lane] * qvl;
      p = wred_sum(p);
      if (lane == 0) se[w][ii] = p;
    }
    __syncthreads();
    float em = -3.4e38f;
    for (int ii = lane; ii < cnt; ii += 64) em = fmaxf(em, se[w][ii]);
    em = wred_max(em);
    float sm = 0.f;
    for (int ii = lane; ii < cnt; ii += 64) sm += __expf(se[w][ii] - em);
    float denom = wred_sum(sm);
    float rp = 0.f;
    for (int ii = 0; ii < cnt; ++ii) rp += __expf(se[w][ii] - em) * act[(size_t)(lo + ii)*64 + lane];
    if (cnt > 0 && denom > 0.f) rp /= denom;
    float s0 = qvl*bf2f(lw[lane*2])     + rp*bf2f(lw[(64 + lane)*2]);
    float s1 = qvl*bf2f(lw[lane*2 + 1]) + rp*bf2f(lw[(64 + lane)*2 + 1]);
    s0 = wred_sum(s0); s1 = wred_sum(s1);
    if (lane == 0){
      store_out(outp, flag, b*2,     s0 + bf2f(lb[0]));
      store_out(outp, flag, b*2 + 1, s1 + bf2f(lb[1]));
    }
  }
}

// ---------------- launcher ----------------

extern "C" void kernel_launch(void* const* d_in, const int* in_sizes, int n_in,
                              void* d_out, int out_size, void* d_ws, size_t ws_size,
                              hipStream_t stream){
  (void)in_sizes; (void)n_in; (void)out_size; (void)ws_size;
  const int* edge_index = (const int*)d_in[2];
  const int* batch      = (const int*)d_in[3];
  const int* stem_idx   = (const int*)d_in[4];
  const int* jbond_idx  = (const int*)d_in[5];

  char* ws = (char*)d_ws;
  size_t off = 0;
  auto alloc = [&](size_t bytes) -> void* {
    void* p = ws + off; off += (bytes + 255) & ~(size_t)255; return p;
  };
  unsigned short* cvt  = (unsigned short*)alloc((size_t)C_TOT * 2);
  unsigned short* w2rt = (unsigned short*)alloc((size_t)64 * KTOT * 2);
  unsigned short* z_bf = (unsigned short*)alloc((size_t)NE * 64 * 2);
  float* actF0 = (float*)alloc((size_t)NN * 64 * 4);
  float* actF1 = (float*)alloc((size_t)NN * 64 * 4);
  unsigned short* actB0 = (unsigned short*)alloc((size_t)NN * 64 * 2);
  unsigned short* actB1 = (unsigned short*)alloc((size_t)NN * 64 * 2);
  float* deg  = (float*)alloc(NN * 4);
  float* agg  = (float*)alloc((size_t)NN * 64 * 4);   // contiguous after deg: one memset
  unsigned short* crt = (unsigned short*)alloc(64 * 64 * 2);
  unsigned short* btg = (unsigned short*)alloc(256 * 128 * 2);
  float* cbg  = (float*)alloc(256 * 4);
  float* qv   = (float*)alloc(64 * 4);
  int* flag   = (int*)alloc(256);

  // deg + agg are adjacent: single memset covers both (agg self-clears in k_gru thereafter)
  hipMemsetAsync(deg, 0, ((size_t)NN * 4) + ((size_t)NN * 64 * 4), stream);

  k_detect<<<1, 256, 0, stream>>>((const unsigned short*)d_in[1], flag);

  CvtArgs ca;
  const int srcIdx[26] = {0,1,6,7,8,9,10,11,12,13,14,15,16,17,18,19,20,21,22,23,24,25,28,29,30,31};
  const int ns[26]  = {114688,65536,896,64,256,64,262144,4096,4096,64,12288,12288,192,192,
                       4096,64,6720,105,4096,64,64,1,256,256,256,2};
  const int ofs[26] = {C_X,C_EA,C_L0W,C_L0B,C_NW1,C_NB1,C_NW2,C_NB2,C_CRT,C_CB,C_GWIH,C_GWHH,
                       C_GBIH,C_GBHH,C_SW1,C_SB1,C_SW2,C_SB2,C_JW1,C_JB1,C_JW2,C_JB2,
                       C_S2IH,C_S2HH,C_LOW,C_LOB};
  for (int j = 0; j < 26; ++j){ ca.src[j] = d_in[srcIdx[j]]; ca.n[j] = ns[j]; ca.off[j] = ofs[j]; }
  k_cvt<<<512, 256, 0, stream>>>(ca, flag, cvt);

  k_setup<<<SETUP_BLOCKS, 256, 0, stream>>>(cvt, edge_index, deg,
                                            actF0, actB0, z_bf, w2rt,
                                            crt, btg, cbg, qv);

  for (int t = 0; t < 6; ++t){
    const float* aF_in  = (t & 1) ? actF1 : actF0;
    float* aF_out       = (t & 1) ? actF0 : actF1;
    const unsigned short* aB_in = (t & 1) ? actB1 : actB0;
    unsigned short* aB_out      = (t & 1) ? actB0 : actB1;
    k_msg<<<(NE/32)*8/4, 256, 0, stream>>>(aB_in, z_bf, w2rt, edge_index, agg);
    k_gru<<<NN/16, 256, 0, stream>>>(aB_in, aF_in, agg, deg, crt, cvt, btg, cbg,
                                     aF_out, aB_out);
  }
  k_heads<<<832, 256, 0, stream>>>(actF0, batch, qv, stem_idx, jbond_idx, cvt, flag, d_out);
}

// Round 7
// 515.715 us; speedup vs baseline: 1.1996x; 1.1996x over previous
//
#include <hip/hip_runtime.h>

#define DIM 64
#define NF 14
#define NOUT 105
#define NN 8192
#define NE 16384
#define NB 256
#define NS 2048
#define NJ 1024
#define KTOT 4160   // 4096 bilinear + 64 bias-fold rows

// ---- internal bf16 arena element offsets ----
#define C_X      0
#define C_EA     114688
#define C_L0W    180224
#define C_L0B    181120
#define C_NW1    181184
#define C_NB1    181440
#define C_NW2    181504
#define C_NB2    443648
#define C_CRT    447744
#define C_CB     451840
#define C_GWIH   451904
#define C_GWHH   464192
#define C_GBIH   476480
#define C_GBHH   476672
#define C_SW1    476864
#define C_SB1    480960
#define C_SW2    481024
#define C_SB2    487744
#define C_JW1    487856
#define C_JB1    491952
#define C_JW2    492016
#define C_JB2    492080
#define C_S2IH   492088
#define C_S2HH   492344
#define C_LOW    492600
#define C_LOB    492856
#define C_TOT    492864

typedef float f32x4 __attribute__((ext_vector_type(4)));
typedef short bf16x8 __attribute__((ext_vector_type(8)));

__device__ __forceinline__ float bf2f(unsigned short u){
  union { unsigned int i; float f; } v; v.i = ((unsigned int)u) << 16; return v.f;
}
__device__ __forceinline__ unsigned short f2bf(float f){
  union { float f; unsigned int i; } v; v.f = f;
  unsigned int x = v.i;
  return (unsigned short)((x + 0x7FFFu + ((x >> 16) & 1u)) >> 16);
}
__device__ __forceinline__ float sigm(float x){ return 1.f / (1.f + __expf(-x)); }
__device__ __forceinline__ float tanh_f(float x){
  x = fminf(10.f, fmaxf(-10.f, x));
  float e = __expf(2.f * x);
  return (e - 1.f) / (e + 1.f);
}
__device__ __forceinline__ float lrelu(float x){ return x > 0.f ? x : 0.01f * x; }

__device__ __forceinline__ float wred_sum(float v){
  #pragma unroll
  for (int off = 32; off > 0; off >>= 1) v += __shfl_xor(v, off, 64);
  return v;
}
__device__ __forceinline__ float wred_max(float v){
  #pragma unroll
  for (int off = 32; off > 0; off >>= 1) v = fmaxf(v, __shfl_xor(v, off, 64));
  return v;
}

// ---------------- dtype detect + convert ----------------

__global__ void k_detect(const unsigned short* __restrict__ ea, int* __restrict__ flag){
  __shared__ int cnt;
  if (threadIdx.x == 0) cnt = 0;
  __syncthreads();
  int c = 0;
  for (int i = threadIdx.x; i < 8192; i += 256) c += (ea[2*i] >> 15) & 1;
  atomicAdd(&cnt, c);
  __syncthreads();
  if (threadIdx.x == 0) *flag = (cnt > 100) ? 1 : 0;  // 1 => inputs are fp32
}

struct CvtArgs {
  const void* src[26];
  int n[26];
  int off[26];
};

__global__ void k_cvt(CvtArgs a, const int* __restrict__ flag, unsigned short* __restrict__ dst){
  bool f32 = (*flag != 0);
  int gid = blockIdx.x * blockDim.x + threadIdx.x, gs = gridDim.x * blockDim.x;
  #pragma unroll 1
  for (int j = 0; j < 26; ++j){
    const void* s = a.src[j];
    int n = a.n[j], o = a.off[j];
    for (int i = gid; i < n; i += gs)
      dst[o + i] = f32 ? f2bf(((const float*)s)[i]) : ((const unsigned short*)s)[i];
  }
}

// ---------------- fused setup: lin0 | edge-net-1 | w2rt build | deg | prep ----------------
// block ranges: [0,2048) lin0, [2048,6144) u/z, [6144,7184) w2rt, [7184,7248) deg, [7248] prep
#define SETUP_BLOCKS 7249

__global__ __launch_bounds__(256) void k_setup(const unsigned short* __restrict__ cvt,
                       const int* __restrict__ ei,
                       float* __restrict__ deg,
                       float* __restrict__ actF, unsigned short* __restrict__ actB,
                       unsigned short* __restrict__ z,
                       unsigned short* __restrict__ w2rt,
                       unsigned short* __restrict__ crt, unsigned short* __restrict__ btg,
                       float* __restrict__ cbg, float* __restrict__ qv){
  int bid = blockIdx.x, tid = threadIdx.x;
  if (bid < 2048){
    const unsigned short* x = cvt + C_X;
    const unsigned short* w = cvt + C_L0W;
    const unsigned short* b = cvt + C_L0B;
    int idx = bid * 256 + tid;
    int n = idx >> 6, d = idx & 63;
    float acc = bf2f(b[d]);
    #pragma unroll
    for (int f = 0; f < NF; ++f) acc += bf2f(x[n*NF + f]) * bf2f(w[f*DIM + d]);
    float v = lrelu(acc);
    actF[idx] = v; actB[idx] = f2bf(v);
  } else if (bid < 6144){
    const unsigned short* ea = cvt + C_EA;
    const unsigned short* w  = cvt + C_NW1;
    const unsigned short* b  = cvt + C_NB1;
    int idx = (bid - 2048) * 256 + tid;
    int e = idx >> 6, d = idx & 63;
    float acc = bf2f(b[d]);
    #pragma unroll
    for (int f = 0; f < 4; ++f) acc += bf2f(ea[e*4 + f]) * bf2f(w[f*DIM + d]);
    z[idx] = f2bf(lrelu(acc));
  } else if (bid < 7184){
    // W2 row-major by output o: w2rt[o][k], k = kz*64 + i  (4096 bilinear) then 64 bias rows
    int idx = (bid - 6144) * 256 + tid;   // exactly 64*KTOT
    const unsigned short* w2 = cvt + C_NW2;
    const unsigned short* b2 = cvt + C_NB2;
    int o = idx / KTOT, k = idx - o * KTOT;
    w2rt[idx] = (k < 4096) ? w2[(k >> 6) * 4096 + (k & 63) * 64 + o]
                           : b2[(k - 4096) * 64 + o];
  } else if (bid < 7248){
    int e = (bid - 7184) * 256 + tid;
    if (e < NE) atomicAdd(&deg[ei[NE + e]], 1.0f);
  } else {
    const unsigned short* cr  = cvt + C_CRT;
    const unsigned short* wih = cvt + C_GWIH;
    const unsigned short* whh = cvt + C_GWHH;
    const unsigned short* bih = cvt + C_GBIH;
    const unsigned short* bhh = cvt + C_GBHH;
    const unsigned short* s2sbih = cvt + C_S2IH;
    const unsigned short* s2sbhh = cvt + C_S2HH;
    for (int t = tid; t < 4096; t += 256){ int n = t & 63, k = t >> 6; crt[n*64 + k] = cr[k*64 + n]; }
    for (int t = tid; t < 32768; t += 256){
      int nidx = t >> 7, kidx = t & 127;
      int g = nidx >> 6, d = nidx & 63, ki = kidx & 63;
      unsigned short v = 0;
      if (kidx < 64){
        if (g == 0) v = wih[ki*192 + d];
        else if (g == 1) v = wih[ki*192 + 64 + d];
        else if (g == 2) v = wih[ki*192 + 128 + d];
      } else {
        if (g == 0) v = whh[ki*192 + d];
        else if (g == 1) v = whh[ki*192 + 64 + d];
        else if (g == 3) v = whh[ki*192 + 128 + d];
      }
      btg[nidx*128 + kidx] = v;
    }
    if (tid < 256){
      int g = tid >> 6, d = tid & 63;
      float v;
      if (g == 0) v = bf2f(bih[d]) + bf2f(bhh[d]);
      else if (g == 1) v = bf2f(bih[64 + d]) + bf2f(bhh[64 + d]);
      else if (g == 2) v = bf2f(bih[128 + d]);
      else v = bf2f(bhh[128 + d]);
      cbg[tid] = v;
    }
    if (tid < 64){
      float gi = bf2f(s2sbih[tid])       + bf2f(s2sbhh[tid]);
      float gg = bf2f(s2sbih[128 + tid]) + bf2f(s2sbhh[128 + tid]);
      float go = bf2f(s2sbih[192 + tid]) + bf2f(s2sbhh[192 + tid]);
      float c = sigm(gi) * tanh_f(gg);
      qv[tid] = sigm(go) * tanh_f(c);
    }
  }
}

// ---------------- per-iteration message: fused rank-1 bilinear GEMM ----------------
// msg[e][o] = sum_{kz,i} z[e][kz] * act[src][i] * W2[kz][i*64+o]  (+ bias rows with zf=1).
// Block = 4 waves sharing ONE 32-edge group; wave w covers kz in [16w,16w+16) (w==3 adds bias).
// Grid = 512 blocks (2/CU, 8 waves/CU). Inner loop = round-4's verbatim-proven code
// (scalar z loads, compiler-scheduled B loads). Per-wave partials -> private LDS slab,
// cross-wave reduce, ONE global atomic per (edge,col) => 1.05M atomics/launch.

__global__ __launch_bounds__(256) void k_msg(const unsigned short* __restrict__ actB,
                                             const unsigned short* __restrict__ z,
                                             const unsigned short* __restrict__ w2rt,
                                             const int* __restrict__ ei,
                                             float* __restrict__ agg){
  __shared__ float smsg[4 * 2048];   // per-wave partial slabs [w][32 rows][64 cols]
  int tid = threadIdx.x;
  int w = tid >> 6, lane = tid & 63;
  int lm = lane & 15, q8 = (lane >> 4) * 8;
  int e0  = blockIdx.x * 32;
  int kz0 = w * 16;

  // A-operand act rows (2 m-tiles x 16 rows, 128B coalesced gather per row)
  uint4 ap[2][2];
  int rowe[2];
  #pragma unroll
  for (int mt = 0; mt < 2; ++mt){
    rowe[mt] = e0 + mt*16 + lm;
    int srcn = ei[rowe[mt]];
    ap[mt][0] = *(const uint4*)&actB[(size_t)srcn*64 + q8];
    ap[mt][1] = *(const uint4*)&actB[(size_t)srcn*64 + 32 + q8];
  }
  // per-lane w2rt row bases (col = nt*16+lm)
  const unsigned short* wrow[4];
  #pragma unroll
  for (int nt = 0; nt < 4; ++nt)
    wrow[nt] = w2rt + (size_t)(nt*16 + lm)*KTOT + q8;

  f32x4 acc[2][4];
  #pragma unroll
  for (int mt = 0; mt < 2; ++mt)
    #pragma unroll
    for (int nt = 0; nt < 4; ++nt) acc[mt][nt] = (f32x4){0.f, 0.f, 0.f, 0.f};

  #pragma unroll 4
  for (int u = 0; u < 16; ++u){
    int kz = kz0 + u;
    // z scalars (L1-resident), one per m-tile row
    float zf[2];
    #pragma unroll
    for (int mt = 0; mt < 2; ++mt)
      zf[mt] = bf2f(z[(size_t)rowe[mt]*64 + kz]);
    #pragma unroll
    for (int h = 0; h < 2; ++h){
      bf16x8 bfr[4];
      #pragma unroll
      for (int nt = 0; nt < 4; ++nt)
        bfr[nt] = *(const bf16x8*)&wrow[nt][kz*64 + h*32];
      #pragma unroll
      for (int mt = 0; mt < 2; ++mt){
        const unsigned int* apw = (const unsigned int*)&ap[mt][h];
        bf16x8 af;
        #pragma unroll
        for (int hh = 0; hh < 4; ++hh){
          float flo = __uint_as_float(apw[hh] << 16) * zf[mt];
          float fhi = __uint_as_float(apw[hh] & 0xFFFF0000u) * zf[mt];
          unsigned int pk;
          asm("v_cvt_pk_bf16_f32 %0, %1, %2" : "=v"(pk) : "v"(flo), "v"(fhi));
          ((unsigned int*)&af)[hh] = pk;
        }
        #pragma unroll
        for (int nt = 0; nt < 4; ++nt)
          acc[mt][nt] = __builtin_amdgcn_mfma_f32_16x16x32_bf16(af, bfr[nt], acc[mt][nt], 0, 0, 0);
      }
    }
  }
  if (w == 3){
    // bias rows (k 4096..4159): A = act directly (zf = 1)
    #pragma unroll
    for (int h = 0; h < 2; ++h){
      bf16x8 bfr[4];
      #pragma unroll
      for (int nt = 0; nt < 4; ++nt)
        bfr[nt] = *(const bf16x8*)&wrow[nt][4096 + h*32];
      #pragma unroll
      for (int mt = 0; mt < 2; ++mt){
        bf16x8 af = *(const bf16x8*)&ap[mt][h];
        #pragma unroll
        for (int nt = 0; nt < 4; ++nt)
          acc[mt][nt] = __builtin_amdgcn_mfma_f32_16x16x32_bf16(af, bfr[nt], acc[mt][nt], 0, 0, 0);
      }
    }
  }
  // per-wave partials -> private LDS slab (plain stores, no atomics)
  {
    int rq = (lane >> 4) * 4;
    float* slab = &smsg[w * 2048];
    #pragma unroll
    for (int mt = 0; mt < 2; ++mt)
      #pragma unroll
      for (int nt = 0; nt < 4; ++nt)
        #pragma unroll
        for (int r = 0; r < 4; ++r)
          slab[(mt*16 + rq + r)*64 + nt*16 + lm] = acc[mt][nt][r];
  }
  __syncthreads();
  // cross-wave reduce + single global atomic per (edge,col)
  for (int idx = tid; idx < 2048; idx += 256){
    int row = idx >> 6, col = idx & 63;
    float s = smsg[idx] + smsg[idx + 2048] + smsg[idx + 4096] + smsg[idx + 6144];
    atomicAdd(&agg[(size_t)ei[NE + e0 + row]*64 + col], s);
  }
}

// ---------------- per-iteration: fused conv_root + GRU (4 waves / 16 nodes) ----------------

__global__ __launch_bounds__(256) void k_gru(const unsigned short* __restrict__ actB_in,
                                             const float* __restrict__ actF_in,
                                             float* __restrict__ agg, const float* __restrict__ deg,
                                             const unsigned short* __restrict__ crt,
                                             const unsigned short* __restrict__ cvt,
                                             const unsigned short* __restrict__ btg,
                                             const float* __restrict__ cbg,
                                             float* __restrict__ actF_out, unsigned short* __restrict__ actB_out){
  const unsigned short* cbias = cvt + C_CB;
  __shared__ __align__(16) unsigned short s_frag[2*4*16*8];  // [kk][q][row][j] A-fragment order
  int w = threadIdx.x >> 6, lane = threadIdx.x & 63;
  int lm = lane & 15, q = lane >> 4;
  int q8 = q*8, rq = q*4;
  int r0 = blockIdx.x * 16;
  // phase 1: wave w computes m for cols [w*16, w*16+16)
  f32x4 am = (f32x4){0.f, 0.f, 0.f, 0.f};
  #pragma unroll
  for (int kk = 0; kk < 2; ++kk){
    bf16x8 a = *(const bf16x8*)&actB_in[(size_t)(r0 + lm)*64 + kk*32 + q8];
    bf16x8 b = *(const bf16x8*)&crt[(size_t)(w*16 + lm)*64 + kk*32 + q8];
    am = __builtin_amdgcn_mfma_f32_16x16x32_bf16(a, b, am, 0, 0, 0);
  }
  {
    int col = w*16 + lm;
    float cb = bf2f(cbias[col]);
    int kk2 = w >> 1, q2 = (w & 1)*2 + (lm >> 3), j = lm & 7;
    #pragma unroll
    for (int r = 0; r < 4; ++r){
      int row = r0 + rq + r;
      float dg = fmaxf(deg[row], 1.f);
      float v = am[r] + agg[(size_t)row*64 + col] / dg + cb;
      agg[(size_t)row*64 + col] = 0.f;   // clear for next iteration
      s_frag[((kk2*4 + q2)*16 + (rq + r))*8 + j] = f2bf(lrelu(v));
    }
  }
  __syncthreads();
  // phase 2: wave w computes gate n-tiles {0,1,2,3}*64 + w*16  (r,z,inn,hn for d-cols w*16..)
  f32x4 g[4];
  #pragma unroll
  for (int t = 0; t < 4; ++t) g[t] = (f32x4){0.f, 0.f, 0.f, 0.f};
  #pragma unroll
  for (int kk = 0; kk < 4; ++kk){
    bf16x8 a;
    if (kk < 2) a = *(const bf16x8*)&s_frag[(kk*4 + q)*128 + lm*8];
    else        a = *(const bf16x8*)&actB_in[(size_t)(r0 + lm)*64 + (kk - 2)*32 + q8];
    #pragma unroll
    for (int t = 0; t < 4; ++t){
      bf16x8 b = *(const bf16x8*)&btg[(size_t)(t*64 + w*16 + lm)*128 + kk*32 + q8];
      g[t] = __builtin_amdgcn_mfma_f32_16x16x32_bf16(a, b, g[t], 0, 0, 0);
    }
  }
  {
    int d = w*16 + lm;
    float cb_r = cbg[d], cb_z = cbg[64 + d], cb_n = cbg[128 + d], cb_h = cbg[192 + d];
    #pragma unroll
    for (int r = 0; r < 4; ++r){
      int row = r0 + rq + r;
      float rr = sigm(g[0][r] + cb_r);
      float zz = sigm(g[1][r] + cb_z);
      float nn = tanh_f(g[2][r] + cb_n + rr * (g[3][r] + cb_h));
      float ho = actF_in[(size_t)row*64 + d];
      float hn2 = (1.f - zz) * nn + zz * ho;
      actF_out[(size_t)row*64 + d] = hn2;
      actB_out[(size_t)row*64 + d] = f2bf(hn2);
    }
  }
}

// ---------------- fused final heads ----------------
// blocks [0,512): stem (4/block) | [512,768): jbond (4/block) | [768,832): graph (4/block, 1 wave each)

__device__ __forceinline__ int lower_bound_batch(const int* b, int val){
  int lo = 0, hi = NN;
  while (lo < hi){ int mid = (lo + hi) >> 1; if (b[mid] < val) lo = mid + 1; else hi = mid; }
  return lo;
}

__device__ __forceinline__ void store_out(void* outp, const int* flag, size_t idx, float v){
  if (*flag) ((float*)outp)[idx] = v;
  else       ((unsigned short*)outp)[idx] = f2bf(v);
}

__global__ __launch_bounds__(256) void k_heads(const float* __restrict__ act,
                                               const int* __restrict__ batch,
                                               const float* __restrict__ qv,
                                               const int* __restrict__ sidx,
                                               const int* __restrict__ jidx,
                                               const unsigned short* __restrict__ cvt,
                                               const int* __restrict__ flag,
                                               void* __restrict__ outp){
  int bid = blockIdx.x;
  int w = threadIdx.x >> 6, lane = threadIdx.x & 63;
  if (bid < 512){
    const unsigned short* w1 = cvt + C_SW1;
    const unsigned short* b1 = cvt + C_SB1;
    const unsigned short* w2 = cvt + C_SW2;
    const unsigned short* b2 = cvt + C_SB2;
    __shared__ float sa[4][64], st[4][64];
    int s = bid * 4 + w;
    int a = sidx[s];
    sa[w][lane] = act[(size_t)a*64 + lane];
    __syncthreads();
    float t = bf2f(b1[lane]);
    #pragma unroll 8
    for (int i = 0; i < 64; ++i) t += sa[w][i] * bf2f(w1[i*64 + lane]);
    st[w][lane] = lrelu(t);
    __syncthreads();
    size_t base = 512 + (size_t)s * NOUT;
    float v = bf2f(b2[lane]);
    #pragma unroll 8
    for (int d = 0; d < 64; ++d) v += st[w][d] * bf2f(w2[d*NOUT + lane]);
    store_out(outp, flag, base + lane, v);
    int o2 = 64 + lane;
    if (o2 < NOUT){
      float v2 = bf2f(b2[o2]);
      #pragma unroll 8
      for (int d = 0; d < 64; ++d) v2 += st[w][d] * bf2f(w2[d*NOUT + o2]);
      store_out(outp, flag, base + o2, v2);
    }
  } else if (bid < 768){
    const unsigned short* w1 = cvt + C_JW1;
    const unsigned short* b1 = cvt + C_JB1;
    const unsigned short* w2 = cvt + C_JW2;
    const unsigned short* b2 = cvt + C_JB2;
    __shared__ float a0[4][64], a1[4][64];
    int j = (bid - 512) * 4 + w;
    int i0 = jidx[j*2], i1 = jidx[j*2 + 1];
    a0[w][lane] = act[(size_t)i0*64 + lane];
    a1[w][lane] = act[(size_t)i1*64 + lane];
    __syncthreads();
    float t0 = bf2f(b1[lane]), t1 = t0;
    #pragma unroll 8
    for (int i = 0; i < 64; ++i){
      float wv = bf2f(w1[i*64 + lane]);
      t0 += a0[w][i] * wv;
      t1 += a1[w][i] * wv;
    }
    t0 = lrelu(t0); t1 = lrelu(t1);
    float p = (t0 + t1) * bf2f(w2[lane]);
    p = wred_sum(p);
    if (lane == 0) store_out(outp, flag, 512 + (size_t)NS*NOUT + j, 0.5f * p + bf2f(b2[0]));
  } else {
    const unsigned short* lw = cvt + C_LOW;
    const unsigned short* lb = cvt + C_LOB;
    __shared__ float se[4][512];
    int b = (bid - 768) * 4 + w;
    int lo = lower_bound_batch(batch, b);
    int hi = lower_bound_batch(batch, b + 1);
    int cnt = hi - lo; if (cnt > 512) cnt = 512;
    float qvl = qv[lane];
    for (int ii = 0; ii < cnt; ++ii){
      float p = act[(size_t)(lo + ii)*64 + lane] * qvl;
      p = wred_sum(p);
      if (lane == 0) se[w][ii] = p;
    }
    __syncthreads();
    float em = -3.4e38f;
    for (int ii = lane; ii < cnt; ii += 64) em = fmaxf(em, se[w][ii]);
    em = wred_max(em);
    float sm = 0.f;
    for (int ii = lane; ii < cnt; ii += 64) sm += __expf(se[w][ii] - em);
    float denom = wred_sum(sm);
    float rp = 0.f;
    for (int ii = 0; ii < cnt; ++ii) rp += __expf(se[w][ii] - em) * act[(size_t)(lo + ii)*64 + lane];
    if (cnt > 0 && denom > 0.f) rp /= denom;
    float s0 = qvl*bf2f(lw[lane*2])     + rp*bf2f(lw[(64 + lane)*2]);
    float s1 = qvl*bf2f(lw[lane*2 + 1]) + rp*bf2f(lw[(64 + lane)*2 + 1]);
    s0 = wred_sum(s0); s1 = wred_sum(s1);
    if (lane == 0){
      store_out(outp, flag, b*2,     s0 + bf2f(lb[0]));
      store_out(outp, flag, b*2 + 1, s1 + bf2f(lb[1]));
    }
  }
}

// ---------------- launcher ----------------

extern "C" void kernel_launch(void* const* d_in, const int* in_sizes, int n_in,
                              void* d_out, int out_size, void* d_ws, size_t ws_size,
                              hipStream_t stream){
  (void)in_sizes; (void)n_in; (void)out_size; (void)ws_size;
  const int* edge_index = (const int*)d_in[2];
  const int* batch      = (const int*)d_in[3];
  const int* stem_idx   = (const int*)d_in[4];
  const int* jbond_idx  = (const int*)d_in[5];

  char* ws = (char*)d_ws;
  size_t off = 0;
  auto alloc = [&](size_t bytes) -> void* {
    void* p = ws + off; off += (bytes + 255) & ~(size_t)255; return p;
  };
  unsigned short* cvt  = (unsigned short*)alloc((size_t)C_TOT * 2);
  unsigned short* w2rt = (unsigned short*)alloc((size_t)64 * KTOT * 2);
  unsigned short* z_bf = (unsigned short*)alloc((size_t)NE * 64 * 2);
  float* actF0 = (float*)alloc((size_t)NN * 64 * 4);
  float* actF1 = (float*)alloc((size_t)NN * 64 * 4);
  unsigned short* actB0 = (unsigned short*)alloc((size_t)NN * 64 * 2);
  unsigned short* actB1 = (unsigned short*)alloc((size_t)NN * 64 * 2);
  float* deg  = (float*)alloc(NN * 4);
  float* agg  = (float*)alloc((size_t)NN * 64 * 4);   // contiguous after deg: one memset
  unsigned short* crt = (unsigned short*)alloc(64 * 64 * 2);
  unsigned short* btg = (unsigned short*)alloc(256 * 128 * 2);
  float* cbg  = (float*)alloc(256 * 4);
  float* qv   = (float*)alloc(64 * 4);
  int* flag   = (int*)alloc(256);

  // deg + agg are adjacent: single memset covers both (agg self-clears in k_gru thereafter)
  hipMemsetAsync(deg, 0, ((size_t)NN * 4) + ((size_t)NN * 64 * 4), stream);

  k_detect<<<1, 256, 0, stream>>>((const unsigned short*)d_in[1], flag);

  CvtArgs ca;
  const int srcIdx[26] = {0,1,6,7,8,9,10,11,12,13,14,15,16,17,18,19,20,21,22,23,24,25,28,29,30,31};
  const int ns[26]  = {114688,65536,896,64,256,64,262144,4096,4096,64,12288,12288,192,192,
                       4096,64,6720,105,4096,64,64,1,256,256,256,2};
  const int ofs[26] = {C_X,C_EA,C_L0W,C_L0B,C_NW1,C_NB1,C_NW2,C_NB2,C_CRT,C_CB,C_GWIH,C_GWHH,
                       C_GBIH,C_GBHH,C_SW1,C_SB1,C_SW2,C_SB2,C_JW1,C_JB1,C_JW2,C_JB2,
                       C_S2IH,C_S2HH,C_LOW,C_LOB};
  for (int j = 0; j < 26; ++j){ ca.src[j] = d_in[srcIdx[j]]; ca.n[j] = ns[j]; ca.off[j] = ofs[j]; }
  k_cvt<<<512, 256, 0, stream>>>(ca, flag, cvt);

  k_setup<<<SETUP_BLOCKS, 256, 0, stream>>>(cvt, edge_index, deg,
                                            actF0, actB0, z_bf, w2rt,
                                            crt, btg, cbg, qv);

  for (int t = 0; t < 6; ++t){
    const float* aF_in  = (t & 1) ? actF1 : actF0;
    float* aF_out       = (t & 1) ? actF0 : actF1;
    const unsigned short* aB_in = (t & 1) ? actB1 : actB0;
    unsigned short* aB_out      = (t & 1) ? actB0 : actB1;
    k_msg<<<NE/32, 256, 0, stream>>>(aB_in, z_bf, w2rt, edge_index, agg);
    k_gru<<<NN/16, 256, 0, stream>>>(aB_in, aF_in, agg, deg, crt, cvt, btg, cbg,
                                     aF_out, aB_out);
  }
  k_heads<<<832, 256, 0, stream>>>(actF0, batch, qv, stem_idx, jbond_idx, cvt, flag, d_out);
}

// Round 8
// 470.422 us; speedup vs baseline: 1.3151x; 1.0963x over previous
//
#include <hip/hip_runtime.h>

#define DIM 64
#define NF 14
#define NOUT 105
#define NN 8192
#define NE 16384
#define NB 256
#define NS 2048
#define NJ 1024
#define KTOT 4160   // 4096 bilinear + 64 bias-fold rows

// ---- internal bf16 arena element offsets ----
#define C_X      0
#define C_EA     114688
#define C_L0W    180224
#define C_L0B    181120
#define C_NW1    181184
#define C_NB1    181440
#define C_NW2    181504
#define C_NB2    443648
#define C_CRT    447744
#define C_CB     451840
#define C_GWIH   451904
#define C_GWHH   464192
#define C_GBIH   476480
#define C_GBHH   476672
#define C_SW1    476864
#define C_SB1    480960
#define C_SW2    481024
#define C_SB2    487744
#define C_JW1    487856
#define C_JB1    491952
#define C_JW2    492016
#define C_JB2    492080
#define C_S2IH   492088
#define C_S2HH   492344
#define C_LOW    492600
#define C_LOB    492856
#define C_TOT    492864

typedef float f32x4 __attribute__((ext_vector_type(4)));
typedef short bf16x8 __attribute__((ext_vector_type(8)));

__device__ __forceinline__ float bf2f(unsigned short u){
  union { unsigned int i; float f; } v; v.i = ((unsigned int)u) << 16; return v.f;
}
__device__ __forceinline__ unsigned short f2bf(float f){
  union { float f; unsigned int i; } v; v.f = f;
  unsigned int x = v.i;
  return (unsigned short)((x + 0x7FFFu + ((x >> 16) & 1u)) >> 16);
}
__device__ __forceinline__ float sigm(float x){ return 1.f / (1.f + __expf(-x)); }
__device__ __forceinline__ float tanh_f(float x){
  x = fminf(10.f, fmaxf(-10.f, x));
  float e = __expf(2.f * x);
  return (e - 1.f) / (e + 1.f);
}
__device__ __forceinline__ float lrelu(float x){ return x > 0.f ? x : 0.01f * x; }

__device__ __forceinline__ float wred_sum(float v){
  #pragma unroll
  for (int off = 32; off > 0; off >>= 1) v += __shfl_xor(v, off, 64);
  return v;
}
__device__ __forceinline__ float wred_max(float v){
  #pragma unroll
  for (int off = 32; off > 0; off >>= 1) v = fmaxf(v, __shfl_xor(v, off, 64));
  return v;
}

// ---------------- dtype detect + convert ----------------

__global__ void k_detect(const unsigned short* __restrict__ ea, int* __restrict__ flag){
  __shared__ int cnt;
  if (threadIdx.x == 0) cnt = 0;
  __syncthreads();
  int c = 0;
  for (int i = threadIdx.x; i < 8192; i += 256) c += (ea[2*i] >> 15) & 1;
  atomicAdd(&cnt, c);
  __syncthreads();
  if (threadIdx.x == 0) *flag = (cnt > 100) ? 1 : 0;  // 1 => inputs are fp32
}

struct CvtArgs {
  const void* src[26];
  int n[26];
  int off[26];
};

__global__ void k_cvt(CvtArgs a, const int* __restrict__ flag, unsigned short* __restrict__ dst){
  bool f32 = (*flag != 0);
  int gid = blockIdx.x * blockDim.x + threadIdx.x, gs = gridDim.x * blockDim.x;
  #pragma unroll 1
  for (int j = 0; j < 26; ++j){
    const void* s = a.src[j];
    int n = a.n[j], o = a.off[j];
    for (int i = gid; i < n; i += gs)
      dst[o + i] = f32 ? f2bf(((const float*)s)[i]) : ((const unsigned short*)s)[i];
  }
}

// ---------------- fused setup: lin0 | edge-net-1 | w2f build | deg | prep ----------------
// block ranges: [0,2048) lin0, [2048,6144) u/z, [6144,7184) w2f, [7184,7248) deg, [7248] prep
#define SETUP_BLOCKS 7249

__global__ __launch_bounds__(256) void k_setup(const unsigned short* __restrict__ cvt,
                       const int* __restrict__ ei,
                       float* __restrict__ deg,
                       float* __restrict__ actF, unsigned short* __restrict__ actB,
                       unsigned short* __restrict__ z,
                       unsigned short* __restrict__ w2f,
                       unsigned short* __restrict__ crt, unsigned short* __restrict__ btg,
                       float* __restrict__ cbg, float* __restrict__ qv){
  int bid = blockIdx.x, tid = threadIdx.x;
  if (bid < 2048){
    const unsigned short* x = cvt + C_X;
    const unsigned short* w = cvt + C_L0W;
    const unsigned short* b = cvt + C_L0B;
    int idx = bid * 256 + tid;
    int n = idx >> 6, d = idx & 63;
    float acc = bf2f(b[d]);
    #pragma unroll
    for (int f = 0; f < NF; ++f) acc += bf2f(x[n*NF + f]) * bf2f(w[f*DIM + d]);
    float v = lrelu(acc);
    actF[idx] = v; actB[idx] = f2bf(v);
  } else if (bid < 6144){
    const unsigned short* ea = cvt + C_EA;
    const unsigned short* w  = cvt + C_NW1;
    const unsigned short* b  = cvt + C_NB1;
    int idx = (bid - 2048) * 256 + tid;
    int e = idx >> 6, d = idx & 63;
    float acc = bf2f(b[d]);
    #pragma unroll
    for (int f = 0; f < 4; ++f) acc += bf2f(ea[e*4 + f]) * bf2f(w[f*DIM + d]);
    z[idx] = f2bf(lrelu(acc));
  } else if (bid < 7184){
    // W2 in MFMA B-fragment order: block f = kz*8 + h*4 + nt  (kz 0..64, unit 64 = bias rows),
    // 512 elems per block: w2f[f*512 + lane*8 + j] = W2[k][o] with
    //   o = nt*16 + (lane&15),  k = kz*64 + h*32 + (lane>>4)*8 + j
    // => a wave's B-load (16B/lane at lane*8) is 1KB CONTIGUOUS.
    int idx = (bid - 6144) * 256 + tid;   // exactly 520*512 = 266240
    const unsigned short* w2 = cvt + C_NW2;
    const unsigned short* b2 = cvt + C_NB2;
    int f = idx >> 9, r = idx & 511;
    int lane = r >> 3, j = r & 7;
    int kz = f >> 3, h = (f >> 2) & 1, nt = f & 3;
    int o = nt*16 + (lane & 15);
    int k = kz*64 + h*32 + (lane >> 4)*8 + j;
    w2f[idx] = (k < 4096) ? w2[(k >> 6)*4096 + (k & 63)*64 + o]
                          : b2[(k - 4096)*64 + o];
  } else if (bid < 7248){
    int e = (bid - 7184) * 256 + tid;
    if (e < NE) atomicAdd(&deg[ei[NE + e]], 1.0f);
  } else {
    const unsigned short* cr  = cvt + C_CRT;
    const unsigned short* wih = cvt + C_GWIH;
    const unsigned short* whh = cvt + C_GWHH;
    const unsigned short* bih = cvt + C_GBIH;
    const unsigned short* bhh = cvt + C_GBHH;
    const unsigned short* s2sbih = cvt + C_S2IH;
    const unsigned short* s2sbhh = cvt + C_S2HH;
    for (int t = tid; t < 4096; t += 256){ int n = t & 63, k = t >> 6; crt[n*64 + k] = cr[k*64 + n]; }
    for (int t = tid; t < 32768; t += 256){
      int nidx = t >> 7, kidx = t & 127;
      int g = nidx >> 6, d = nidx & 63, ki = kidx & 63;
      unsigned short v = 0;
      if (kidx < 64){
        if (g == 0) v = wih[ki*192 + d];
        else if (g == 1) v = wih[ki*192 + 64 + d];
        else if (g == 2) v = wih[ki*192 + 128 + d];
      } else {
        if (g == 0) v = whh[ki*192 + d];
        else if (g == 1) v = whh[ki*192 + 64 + d];
        else if (g == 3) v = whh[ki*192 + 128 + d];
      }
      btg[nidx*128 + kidx] = v;
    }
    if (tid < 256){
      int g = tid >> 6, d = tid & 63;
      float v;
      if (g == 0) v = bf2f(bih[d]) + bf2f(bhh[d]);
      else if (g == 1) v = bf2f(bih[64 + d]) + bf2f(bhh[64 + d]);
      else if (g == 2) v = bf2f(bih[128 + d]);
      else v = bf2f(bhh[128 + d]);
      cbg[tid] = v;
    }
    if (tid < 64){
      float gi = bf2f(s2sbih[tid])       + bf2f(s2sbhh[tid]);
      float gg = bf2f(s2sbih[128 + tid]) + bf2f(s2sbhh[128 + tid]);
      float go = bf2f(s2sbih[192 + tid]) + bf2f(s2sbhh[192 + tid]);
      float c = sigm(gi) * tanh_f(gg);
      qv[tid] = sigm(go) * tanh_f(c);
    }
  }
}

// ---------------- per-iteration message: fused rank-1 bilinear GEMM ----------------
// msg[e][o] = sum_{kz,i} z[e][kz] * act[src][i] * W2[kz][i*64+o]  (+ bias rows with zf=1).
// Grid = 1024: block b covers edge-group g=b>>1 (32 edges) and K-half kh=b&1;
// wave w handles kz in [kh*32 + 8w, +8)  (kh==1,w==3 adds the bias unit kz=64).
// 4 blocks/CU = 16 waves/CU. B-loads are 1KB-contiguous per wave (w2f fragment order).
// Per-wave partials -> private LDS slab, cross-wave reduce, one atomic per (edge,col,kh).

__global__ __launch_bounds__(256) void k_msg(const unsigned short* __restrict__ actB,
                                             const unsigned short* __restrict__ z,
                                             const unsigned short* __restrict__ w2f,
                                             const int* __restrict__ ei,
                                             float* __restrict__ agg){
  __shared__ float smsg[4 * 2048];   // per-wave partial slabs [w][32 rows][64 cols]
  int tid = threadIdx.x;
  int w = tid >> 6, lane = tid & 63;
  int lm = lane & 15, q8 = (lane >> 4) * 8;
  int g  = blockIdx.x >> 1, kh = blockIdx.x & 1;
  int e0  = g * 32;
  int kz0 = kh * 32 + w * 8;

  // A-operand act rows (2 m-tiles x 16 rows, 128B coalesced gather per row)
  uint4 ap[2][2];
  int rowe[2];
  #pragma unroll
  for (int mt = 0; mt < 2; ++mt){
    rowe[mt] = e0 + mt*16 + lm;
    int srcn = ei[rowe[mt]];
    ap[mt][0] = *(const uint4*)&actB[(size_t)srcn*64 + q8];
    ap[mt][1] = *(const uint4*)&actB[(size_t)srcn*64 + 32 + q8];
  }

  f32x4 acc[2][4];
  #pragma unroll
  for (int mt = 0; mt < 2; ++mt)
    #pragma unroll
    for (int nt = 0; nt < 4; ++nt) acc[mt][nt] = (f32x4){0.f, 0.f, 0.f, 0.f};

  #pragma unroll 2
  for (int u = 0; u < 8; ++u){
    int kz = kz0 + u;
    // z scalars (L2-resident), one per m-tile row
    float zf[2];
    #pragma unroll
    for (int mt = 0; mt < 2; ++mt)
      zf[mt] = bf2f(z[(size_t)rowe[mt]*64 + kz]);
    #pragma unroll
    for (int h = 0; h < 2; ++h){
      bf16x8 bfr[4];
      #pragma unroll
      for (int nt = 0; nt < 4; ++nt)
        bfr[nt] = *(const bf16x8*)&w2f[(size_t)(kz*8 + h*4 + nt)*512 + lane*8];
      #pragma unroll
      for (int mt = 0; mt < 2; ++mt){
        const unsigned int* apw = (const unsigned int*)&ap[mt][h];
        bf16x8 af;
        #pragma unroll
        for (int hh = 0; hh < 4; ++hh){
          float flo = __uint_as_float(apw[hh] << 16) * zf[mt];
          float fhi = __uint_as_float(apw[hh] & 0xFFFF0000u) * zf[mt];
          unsigned int pk;
          asm("v_cvt_pk_bf16_f32 %0, %1, %2" : "=v"(pk) : "v"(flo), "v"(fhi));
          ((unsigned int*)&af)[hh] = pk;
        }
        #pragma unroll
        for (int nt = 0; nt < 4; ++nt)
          acc[mt][nt] = __builtin_amdgcn_mfma_f32_16x16x32_bf16(af, bfr[nt], acc[mt][nt], 0, 0, 0);
      }
    }
  }
  if (kh == 1 && w == 3){
    // bias unit kz=64 (k 4096..4159): A = act directly (zf = 1)
    #pragma unroll
    for (int h = 0; h < 2; ++h){
      bf16x8 bfr[4];
      #pragma unroll
      for (int nt = 0; nt < 4; ++nt)
        bfr[nt] = *(const bf16x8*)&w2f[(size_t)(512 + h*4 + nt)*512 + lane*8];
      #pragma unroll
      for (int mt = 0; mt < 2; ++mt){
        bf16x8 af = *(const bf16x8*)&ap[mt][h];
        #pragma unroll
        for (int nt = 0; nt < 4; ++nt)
          acc[mt][nt] = __builtin_amdgcn_mfma_f32_16x16x32_bf16(af, bfr[nt], acc[mt][nt], 0, 0, 0);
      }
    }
  }
  // per-wave partials -> private LDS slab (plain stores, no atomics)
  {
    int rq = (lane >> 4) * 4;
    float* slab = &smsg[w * 2048];
    #pragma unroll
    for (int mt = 0; mt < 2; ++mt)
      #pragma unroll
      for (int nt = 0; nt < 4; ++nt)
        #pragma unroll
        for (int r = 0; r < 4; ++r)
          slab[(mt*16 + rq + r)*64 + nt*16 + lm] = acc[mt][nt][r];
  }
  __syncthreads();
  // cross-wave reduce + one global atomic per (edge,col)
  for (int idx = tid; idx < 2048; idx += 256){
    int row = idx >> 6, col = idx & 63;
    float s = smsg[idx] + smsg[idx + 2048] + smsg[idx + 4096] + smsg[idx + 6144];
    atomicAdd(&agg[(size_t)ei[NE + e0 + row]*64 + col], s);
  }
}

// ---------------- per-iteration: fused conv_root + GRU (4 waves / 16 nodes) ----------------

__global__ __launch_bounds__(256) void k_gru(const unsigned short* __restrict__ actB_in,
                                             const float* __restrict__ actF_in,
                                             float* __restrict__ agg, const float* __restrict__ deg,
                                             const unsigned short* __restrict__ crt,
                                             const unsigned short* __restrict__ cvt,
                                             const unsigned short* __restrict__ btg,
                                             const float* __restrict__ cbg,
                                             float* __restrict__ actF_out, unsigned short* __restrict__ actB_out){
  const unsigned short* cbias = cvt + C_CB;
  __shared__ __align__(16) unsigned short s_frag[2*4*16*8];  // [kk][q][row][j] A-fragment order
  int w = threadIdx.x >> 6, lane = threadIdx.x & 63;
  int lm = lane & 15, q = lane >> 4;
  int q8 = q*8, rq = q*4;
  int r0 = blockIdx.x * 16;
  // phase 1: wave w computes m for cols [w*16, w*16+16)
  f32x4 am = (f32x4){0.f, 0.f, 0.f, 0.f};
  #pragma unroll
  for (int kk = 0; kk < 2; ++kk){
    bf16x8 a = *(const bf16x8*)&actB_in[(size_t)(r0 + lm)*64 + kk*32 + q8];
    bf16x8 b = *(const bf16x8*)&crt[(size_t)(w*16 + lm)*64 + kk*32 + q8];
    am = __builtin_amdgcn_mfma_f32_16x16x32_bf16(a, b, am, 0, 0, 0);
  }
  {
    int col = w*16 + lm;
    float cb = bf2f(cbias[col]);
    int kk2 = w >> 1, q2 = (w & 1)*2 + (lm >> 3), j = lm & 7;
    #pragma unroll
    for (int r = 0; r < 4; ++r){
      int row = r0 + rq + r;
      float dg = fmaxf(deg[row], 1.f);
      float v = am[r] + agg[(size_t)row*64 + col] / dg + cb;
      agg[(size_t)row*64 + col] = 0.f;   // clear for next iteration
      s_frag[((kk2*4 + q2)*16 + (rq + r))*8 + j] = f2bf(lrelu(v));
    }
  }
  __syncthreads();
  // phase 2: wave w computes gate n-tiles {0,1,2,3}*64 + w*16  (r,z,inn,hn for d-cols w*16..)
  f32x4 g[4];
  #pragma unroll
  for (int t = 0; t < 4; ++t) g[t] = (f32x4){0.f, 0.f, 0.f, 0.f};
  #pragma unroll
  for (int kk = 0; kk < 4; ++kk){
    bf16x8 a;
    if (kk < 2) a = *(const bf16x8*)&s_frag[(kk*4 + q)*128 + lm*8];
    else        a = *(const bf16x8*)&actB_in[(size_t)(r0 + lm)*64 + (kk - 2)*32 + q8];
    #pragma unroll
    for (int t = 0; t < 4; ++t){
      bf16x8 b = *(const bf16x8*)&btg[(size_t)(t*64 + w*16 + lm)*128 + kk*32 + q8];
      g[t] = __builtin_amdgcn_mfma_f32_16x16x32_bf16(a, b, g[t], 0, 0, 0);
    }
  }
  {
    int d = w*16 + lm;
    float cb_r = cbg[d], cb_z = cbg[64 + d], cb_n = cbg[128 + d], cb_h = cbg[192 + d];
    #pragma unroll
    for (int r = 0; r < 4; ++r){
      int row = r0 + rq + r;
      float rr = sigm(g[0][r] + cb_r);
      float zz = sigm(g[1][r] + cb_z);
      float nn = tanh_f(g[2][r] + cb_n + rr * (g[3][r] + cb_h));
      float ho = actF_in[(size_t)row*64 + d];
      float hn2 = (1.f - zz) * nn + zz * ho;
      actF_out[(size_t)row*64 + d] = hn2;
      actB_out[(size_t)row*64 + d] = f2bf(hn2);
    }
  }
}

// ---------------- fused final heads ----------------
// blocks [0,512): stem (4/block) | [512,768): jbond (4/block) | [768,832): graph (4/block, 1 wave each)

__device__ __forceinline__ int lower_bound_batch(const int* b, int val){
  int lo = 0, hi = NN;
  while (lo < hi){ int mid = (lo + hi) >> 1; if (b[mid] < val) lo = mid + 1; else hi = mid; }
  return lo;
}

__device__ __forceinline__ void store_out(void* outp, const int* flag, size_t idx, float v){
  if (*flag) ((float*)outp)[idx] = v;
  else       ((unsigned short*)outp)[idx] = f2bf(v);
}

__global__ __launch_bounds__(256) void k_heads(const float* __restrict__ act,
                                               const int* __restrict__ batch,
                                               const float* __restrict__ qv,
                                               const int* __restrict__ sidx,
                                               const int* __restrict__ jidx,
                                               const unsigned short* __restrict__ cvt,
                                               const int* __restrict__ flag,
                                               void* __restrict__ outp){
  int bid = blockIdx.x;
  int w = threadIdx.x >> 6, lane = threadIdx.x & 63;
  if (bid < 512){
    const unsigned short* w1 = cvt + C_SW1;
    const unsigned short* b1 = cvt + C_SB1;
    const unsigned short* w2 = cvt + C_SW2;
    const unsigned short* b2 = cvt + C_SB2;
    __shared__ float sa[4][64], st[4][64];
    int s = bid * 4 + w;
    int a = sidx[s];
    sa[w][lane] = act[(size_t)a*64 + lane];
    __syncthreads();
    float t = bf2f(b1[lane]);
    #pragma unroll 8
    for (int i = 0; i < 64; ++i) t += sa[w][i] * bf2f(w1[i*64 + lane]);
    st[w][lane] = lrelu(t);
    __syncthreads();
    size_t base = 512 + (size_t)s * NOUT;
    float v = bf2f(b2[lane]);
    #pragma unroll 8
    for (int d = 0; d < 64; ++d) v += st[w][d] * bf2f(w2[d*NOUT + lane]);
    store_out(outp, flag, base + lane, v);
    int o2 = 64 + lane;
    if (o2 < NOUT){
      float v2 = bf2f(b2[o2]);
      #pragma unroll 8
      for (int d = 0; d < 64; ++d) v2 += st[w][d] * bf2f(w2[d*NOUT + o2]);
      store_out(outp, flag, base + o2, v2);
    }
  } else if (bid < 768){
    const unsigned short* w1 = cvt + C_JW1;
    const unsigned short* b1 = cvt + C_JB1;
    const unsigned short* w2 = cvt + C_JW2;
    const unsigned short* b2 = cvt + C_JB2;
    __shared__ float a0[4][64], a1[4][64];
    int j = (bid - 512) * 4 + w;
    int i0 = jidx[j*2], i1 = jidx[j*2 + 1];
    a0[w][lane] = act[(size_t)i0*64 + lane];
    a1[w][lane] = act[(size_t)i1*64 + lane];
    __syncthreads();
    float t0 = bf2f(b1[lane]), t1 = t0;
    #pragma unroll 8
    for (int i = 0; i < 64; ++i){
      float wv = bf2f(w1[i*64 + lane]);
      t0 += a0[w][i] * wv;
      t1 += a1[w][i] * wv;
    }
    t0 = lrelu(t0); t1 = lrelu(t1);
    float p = (t0 + t1) * bf2f(w2[lane]);
    p = wred_sum(p);
    if (lane == 0) store_out(outp, flag, 512 + (size_t)NS*NOUT + j, 0.5f * p + bf2f(b2[0]));
  } else {
    const unsigned short* lw = cvt + C_LOW;
    const unsigned short* lb = cvt + C_LOB;
    __shared__ float se[4][512];
    int b = (bid - 768) * 4 + w;
    int lo = lower_bound_batch(batch, b);
    int hi = lower_bound_batch(batch, b + 1);
    int cnt = hi - lo; if (cnt > 512) cnt = 512;
    float qvl = qv[lane];
    for (int ii = 0; ii < cnt; ++ii){
      float p = act[(size_t)(lo + ii)*64 + lane] * qvl;
      p = wred_sum(p);
      if (lane == 0) se[w][ii] = p;
    }
    __syncthreads();
    float em = -3.4e38f;
    for (int ii = lane; ii < cnt; ii += 64) em = fmaxf(em, se[w][ii]);
    em = wred_max(em);
    float sm = 0.f;
    for (int ii = lane; ii < cnt; ii += 64) sm += __expf(se[w][ii] - em);
    float denom = wred_sum(sm);
    float rp = 0.f;
    for (int ii = 0; ii < cnt; ++ii) rp += __expf(se[w][ii] - em) * act[(size_t)(lo + ii)*64 + lane];
    if (cnt > 0 && denom > 0.f) rp /= denom;
    float s0 = qvl*bf2f(lw[lane*2])     + rp*bf2f(lw[(64 + lane)*2]);
    float s1 = qvl*bf2f(lw[lane*2 + 1]) + rp*bf2f(lw[(64 + lane)*2 + 1]);
    s0 = wred_sum(s0); s1 = wred_sum(s1);
    if (lane == 0){
      store_out(outp, flag, b*2,     s0 + bf2f(lb[0]));
      store_out(outp, flag, b*2 + 1, s1 + bf2f(lb[1]));
    }
  }
}

// ---------------- launcher ----------------

extern "C" void kernel_launch(void* const* d_in, const int* in_sizes, int n_in,
                              void* d_out, int out_size, void* d_ws, size_t ws_size,
                              hipStream_t stream){
  (void)in_sizes; (void)n_in; (void)out_size; (void)ws_size;
  const int* edge_index = (const int*)d_in[2];
  const int* batch      = (const int*)d_in[3];
  const int* stem_idx   = (const int*)d_in[4];
  const int* jbond_idx  = (const int*)d_in[5];

  char* ws = (char*)d_ws;
  size_t off = 0;
  auto alloc = [&](size_t bytes) -> void* {
    void* p = ws + off; off += (bytes + 255) & ~(size_t)255; return p;
  };
  unsigned short* cvt  = (unsigned short*)alloc((size_t)C_TOT * 2);
  unsigned short* w2f  = (unsigned short*)alloc((size_t)64 * KTOT * 2);   // 520 frag-blocks x 512
  unsigned short* z_bf = (unsigned short*)alloc((size_t)NE * 64 * 2);
  float* actF0 = (float*)alloc((size_t)NN * 64 * 4);
  float* actF1 = (float*)alloc((size_t)NN * 64 * 4);
  unsigned short* actB0 = (unsigned short*)alloc((size_t)NN * 64 * 2);
  unsigned short* actB1 = (unsigned short*)alloc((size_t)NN * 64 * 2);
  float* deg  = (float*)alloc(NN * 4);
  float* agg  = (float*)alloc((size_t)NN * 64 * 4);   // contiguous after deg: one memset
  unsigned short* crt = (unsigned short*)alloc(64 * 64 * 2);
  unsigned short* btg = (unsigned short*)alloc(256 * 128 * 2);
  float* cbg  = (float*)alloc(256 * 4);
  float* qv   = (float*)alloc(64 * 4);
  int* flag   = (int*)alloc(256);

  // deg + agg are adjacent: single memset covers both (agg self-clears in k_gru thereafter)
  hipMemsetAsync(deg, 0, ((size_t)NN * 4) + ((size_t)NN * 64 * 4), stream);

  k_detect<<<1, 256, 0, stream>>>((const unsigned short*)d_in[1], flag);

  CvtArgs ca;
  const int srcIdx[26] = {0,1,6,7,8,9,10,11,12,13,14,15,16,17,18,19,20,21,22,23,24,25,28,29,30,31};
  const int ns[26]  = {114688,65536,896,64,256,64,262144,4096,4096,64,12288,12288,192,192,
                       4096,64,6720,105,4096,64,64,1,256,256,256,2};
  const int ofs[26] = {C_X,C_EA,C_L0W,C_L0B,C_NW1,C_NB1,C_NW2,C_NB2,C_CRT,C_CB,C_GWIH,C_GWHH,
                       C_GBIH,C_GBHH,C_SW1,C_SB1,C_SW2,C_SB2,C_JW1,C_JB1,C_JW2,C_JB2,
                       C_S2IH,C_S2HH,C_LOW,C_LOB};
  for (int j = 0; j < 26; ++j){ ca.src[j] = d_in[srcIdx[j]]; ca.n[j] = ns[j]; ca.off[j] = ofs[j]; }
  k_cvt<<<512, 256, 0, stream>>>(ca, flag, cvt);

  k_setup<<<SETUP_BLOCKS, 256, 0, stream>>>(cvt, edge_index, deg,
                                            actF0, actB0, z_bf, w2f,
                                            crt, btg, cbg, qv);

  for (int t = 0; t < 6; ++t){
    const float* aF_in  = (t & 1) ? actF1 : actF0;
    float* aF_out       = (t & 1) ? actF0 : actF1;
    const unsigned short* aB_in = (t & 1) ? actB1 : actB0;
    unsigned short* aB_out      = (t & 1) ? actB0 : actB1;
    k_msg<<<(NE/32)*2, 256, 0, stream>>>(aB_in, z_bf, w2f, edge_index, agg);
    k_gru<<<NN/16, 256, 0, stream>>>(aB_in, aF_in, agg, deg, crt, cvt, btg, cbg,
                                     aF_out, aB_out);
  }
  k_heads<<<832, 256, 0, stream>>>(actF0, batch, qv, stem_idx, jbond_idx, cvt, flag, d_out);
}